// Round 13
// baseline (75.521 us; speedup 1.0000x reference)
//
#include <hip/hip_runtime.h>

typedef unsigned long long u64;
typedef unsigned int u32;
typedef unsigned short u16;

#define N_DET 4096
#define NW 64               // 4096 bits = 64 u64 words
#define IOU_TR 0.3f
#define SCORE_TR 0.1f
#define EPS 1e-9f

// ---------------------------------------------------------------------------
// ws layout:
//   rows    : 4096*8 f32  (sorted detection rows)         128 KB
//   soa     : 7*4096 f32  (lox,loy,loz,hix,hiy,hiz,vol)   112 KB
//   A       : 64 u64      (bit i = suppression row i nonempty)
//   counter : 16 u32      (last-block counter, padded)
//   Trm     : 4096*64 u64 row-major bitmatrix; only nonempty rows written.
// 2 dispatches: k_sort, k_supscan = R8's proven sup + last-block tail
// running R8's proven scan + output. NO new algorithmic pieces.
// LEDGER: R8 59.4 best (4 disp). Fused tail runs at standalone speed
// (R7 re-analysis); R7/R9 regression = ov-branch; R11 = edge-walk;
// R12 = 2-row sup / mirror-scan (+6). All discarded.
// ---------------------------------------------------------------------------

__device__ __forceinline__ u64 rl64(u64 v, int l) {
    unsigned lo = __builtin_amdgcn_readlane((unsigned)v, l);
    unsigned hi = __builtin_amdgcn_readlane((unsigned)(v >> 32), l);
    return ((u64)hi << 32) | lo;
}

// K1: stable descending rank sort (R8 exact) + zero A/counter.
__global__ void __launch_bounds__(256) k_sort(const float* __restrict__ res,
                                              float* __restrict__ rows,
                                              float* __restrict__ soa,
                                              u64* __restrict__ A,
                                              u32* __restrict__ counter) {
    __shared__ float s[N_DET];
    int tid = threadIdx.x;
    if (blockIdx.x == 0) {
        if (tid < 64) A[tid] = 0ull;
        if (tid == 64) *counter = 0u;
    }
    for (int j = tid; j < N_DET; j += 256) s[j] = res[j * 8];
    __syncthreads();
    int r = tid >> 4, c = tid & 15;
    int gi = blockIdx.x * 16 + r;
    float sc = s[gi];
    int part = 0;
    int j0 = c * 256;
    for (int j = j0; j < j0 + 256; ++j) {
        float sj = s[j];
        part += (sj > sc) || (sj == sc && j < gi);
    }
    part += __shfl_xor(part, 1, 64);
    part += __shfl_xor(part, 2, 64);
    part += __shfl_xor(part, 4, 64);
    part += __shfl_xor(part, 8, 64);
    if (c == 0) {
        int rank = part;
        float4 a = *(const float4*)(res + gi * 8);
        float4 b = *(const float4*)(res + gi * 8 + 4);
        *(float4*)(rows + rank * 8)     = a;
        *(float4*)(rows + rank * 8 + 4) = b;
        // a = (score, class, cx, cy); b = (cz, dx, dy, dz)
        float cx = a.z, cy = a.w, cz = b.x, dx = b.y, dy = b.z, dz = b.w;
        soa[0 * N_DET + rank] = cx - dx * 0.5f;
        soa[1 * N_DET + rank] = cy - dy * 0.5f;
        soa[2 * N_DET + rank] = cz - dz * 0.5f;
        soa[3 * N_DET + rank] = cx + dx * 0.5f;
        soa[4 * N_DET + rank] = cy + dy * 0.5f;
        soa[5 * N_DET + rank] = cz + dz * 0.5f;
        soa[6 * N_DET + rank] = (dx * dy) * dz;   // np.prod order ((dx*dy)*dz)
    }
}

// K2: R8 sup (one row per wave, upper-tri, straight-line) + last-block tail
// (R8 scan: valid ballots, nlist build, 32-deep pipelined readlane chain;
// then R8 gated output).
#define FIDX(V, GB) { V = (u32)s_nlist[(GB) + (lane & 15)]; }

#define IS1(V, P, S) { u32 si_ = (u32)__builtin_amdgcn_readlane((V), (S)); \
    P##S = Trm[(size_t)si_ * NW + lane]; }

#define IS16(V, P) IS1(V,P,0) IS1(V,P,1) IS1(V,P,2) IS1(V,P,3)   \
    IS1(V,P,4) IS1(V,P,5) IS1(V,P,6) IS1(V,P,7)                  \
    IS1(V,P,8) IS1(V,P,9) IS1(V,P,10) IS1(V,P,11)                \
    IS1(V,P,12) IS1(V,P,13) IS1(V,P,14) IS1(V,P,15)

#define PR1(V, P, S) { u32 si_ = (u32)__builtin_amdgcn_readlane((V), (S)); \
    u64 awd_ = rl64(act, (int)(si_ >> 6));                                 \
    u64 bit_ = (awd_ >> (si_ & 63u)) & 1ull;                               \
    u64 m_ = (0ull - bit_) & (0ull - (u64)(si_ != 4095u));                 \
    act &= ~(P##S & m_); }

#define PR16(V, P) PR1(V,P,0) PR1(V,P,1) PR1(V,P,2) PR1(V,P,3)   \
    PR1(V,P,4) PR1(V,P,5) PR1(V,P,6) PR1(V,P,7)                  \
    PR1(V,P,8) PR1(V,P,9) PR1(V,P,10) PR1(V,P,11)                \
    PR1(V,P,12) PR1(V,P,13) PR1(V,P,14) PR1(V,P,15)

__global__ void __launch_bounds__(256, 1)
k_supscan(const float* __restrict__ soa, const float* __restrict__ rows,
          u64* __restrict__ Trm, u64* __restrict__ A,
          u32* __restrict__ counter, float* __restrict__ out) {
    __shared__ u64 s_valid[NW];
    __shared__ u64 s_keep[NW];
    __shared__ u16 s_nlist[4224];
    __shared__ int s_last;
    const int tid = threadIdx.x;
    const int wv = tid >> 6;
    const int lane = tid & 63;

    // ---- sup phase (R8 exact body): one wave per row i ----
    {
        int i = blockIdx.x * 4 + wv;
        float ilox = soa[0*N_DET+i], iloy = soa[1*N_DET+i], iloz = soa[2*N_DET+i];
        float ihix = soa[3*N_DET+i], ihiy = soa[4*N_DET+i], ihiz = soa[5*N_DET+i];
        float ivol = soa[6*N_DET+i];
        u64 rowword = 0, rowOr = 0;
        for (int w = (i >> 6); w < NW; ++w) {
            int j = w * 64 + lane;
            float lox = soa[0*N_DET+j], loy = soa[1*N_DET+j], loz = soa[2*N_DET+j];
            float hix = soa[3*N_DET+j], hiy = soa[4*N_DET+j], hiz = soa[5*N_DET+j];
            float vol = soa[6*N_DET+j];
            float ix = fminf(ihix,hix)-fmaxf(ilox,lox); ix = fmaxf(ix,0.f);
            float iy = fminf(ihiy,hiy)-fmaxf(iloy,loy); iy = fmaxf(iy,0.f);
            float iz = fminf(ihiz,hiz)-fmaxf(iloz,loz); iz = fmaxf(iz,0.f);
            float inter = (ix * iy) * iz;             // ((x*y)*z) like np.prod
            float uni = ivol + vol - inter;           // (vol_i+vol_j)-inter
            float iou = inter / (uni + EPS);          // IEEE div
            bool sb = (iou > IOU_TR) && (j > i);
            u64 m = __ballot(sb);
            rowOr |= m;
            rowword = (lane == w) ? m : rowword;
        }
        if (rowOr) {                                  // wave-uniform branch
            Trm[(size_t)i * NW + lane] = rowword;     // coalesced 512B store
            if (lane == 0) atomicOr(&A[i >> 6], 1ull << (i & 63));
        }
    }
    __syncthreads();
    if (tid == 0) {
        __threadfence();                              // release Trm/A stores
        u32 old = atomicAdd(counter, 1u);
        s_last = (old == (u32)(gridDim.x - 1));
    }
    __syncthreads();
    if (!s_last) return;
    __threadfence();                                  // acquire all stores

    // ---- tail (last block): R8 scan ----
    for (int w = wv * 16; w < wv * 16 + 16; ++w) {
        float scw = rows[(w * 64 + lane) * 8];
        u64 m = __ballot(scw >= SCORE_TR);
        if (lane == 0) s_valid[w] = m;
    }
    __syncthreads();

    if (wv == 0) {
        u64 act = s_valid[lane];
        u64 avA = A[lane];
        int pc = __popcll(avA);
        int inc = pc;
#pragma unroll
        for (int d = 1; d < 64; d <<= 1) {
            int t = __shfl_up(inc, d, 64);
            if (lane >= d) inc += t;
        }
        int exc = inc - pc;
        int nTotal = __shfl(inc, 63, 64);
        {   // emit this lane's nonempty-row indices (globally sorted)
            u64 m = avA; int o = exc;
            while (m) {
                int k = __builtin_ctzll(m); m &= m - 1;
                s_nlist[o++] = (u16)(lane * 64 + k);
            }
        }
        int padded = (nTotal + 63) & ~63;
        for (int t = nTotal + lane; t < padded + 128; t += 64)
            s_nlist[t] = (u16)4095;
        __threadfence_block();                 // wave-local LDS ordering

        if (padded > 0) {                      // padded is a multiple of 64
            u64 pa0,pa1,pa2,pa3,pa4,pa5,pa6,pa7,
                pa8,pa9,pa10,pa11,pa12,pa13,pa14,pa15;
            u64 pb0,pb1,pb2,pb3,pb4,pb5,pb6,pb7,
                pb8,pb9,pb10,pb11,pb12,pb13,pb14,pb15;
            u32 iA0, iA1, iB0, iB1;
            FIDX(iA0, 0)  IS16(iA0, pa)
            FIDX(iB0, 16) IS16(iB0, pb)
            int g = 0;
            while (g < padded) {
                FIDX(iA1, g + 32)
                PR16(iA0, pa)                  // rows g..g+15
                IS16(iA1, pa)                  // issue g+32
                FIDX(iB1, g + 48)
                PR16(iB0, pb)                  // rows g+16..g+31
                IS16(iB1, pb)                  // issue g+48
                g += 32;
                if (g >= padded) break;
                FIDX(iA0, g + 32)
                PR16(iA1, pa)
                IS16(iA0, pa)
                FIDX(iB0, g + 48)
                PR16(iB1, pb)
                IS16(iB0, pb)
                g += 32;
            }
        }
        s_keep[lane] = act;                    // final act == keep mask
    }
    __syncthreads();

    // ---- gated output (R8 exact): 256 threads x 16 rows, coalesced ----
    for (int n = 0; n < 16; ++n) {
        int i = n * 256 + tid;
        bool kp = (s_keep[i >> 6] >> (i & 63)) & 1ull;
        float4 a = kp ? ((const float4*)rows)[i * 2]     : make_float4(0.f, 0.f, 0.f, 0.f);
        float4 b = kp ? ((const float4*)rows)[i * 2 + 1] : make_float4(0.f, 0.f, 0.f, 0.f);
        ((float4*)out)[i * 2]     = a;
        ((float4*)out)[i * 2 + 1] = b;
    }
}

extern "C" void kernel_launch(void* const* d_in, const int* in_sizes, int n_in,
                              void* d_out, int out_size, void* d_ws, size_t ws_size,
                              hipStream_t stream) {
    const float* res = (const float*)d_in[0];
    float* out = (float*)d_out;

    float* rows  = (float*)d_ws;                      // 32768 f32
    float* soa   = rows + N_DET * 8;                  // 28672 f32
    u64*   A     = (u64*)(soa + 7 * N_DET);           // 64 u64
    u32*   counter = (u32*)(A + NW);                  // 16 u32 (padded)
    u64*   Trm   = (u64*)(counter + 16);              // 4096*64 u64 (row-major)

    k_sort   <<<N_DET / 16, 256, 0, stream>>>(res, rows, soa, A, counter);
    k_supscan<<<N_DET / 4, 256, 0, stream>>>(soa, rows, Trm, A, counter, out);
}

// Round 14
// 61.657 us; speedup vs baseline: 1.2249x; 1.2249x over previous
//
#include <hip/hip_runtime.h>

typedef unsigned long long u64;
typedef unsigned int u32;
typedef unsigned short u16;

#define N_DET 4096
#define NW 64               // 4096 bits = 64 u64 words
#define IOU_TR 0.3f
#define SCORE_TR 0.1f
#define EPS 1e-9f

// ---------------------------------------------------------------------------
// ws layout (R8 layout):
//   rows : 4096*8 f32  (sorted detection rows)         128 KB
//   soa  : 7*4096 f32  (lox,loy,loz,hix,hiy,hiz,vol)   112 KB
//   A    : 64 u64      (bit i = suppression row i nonempty)
//   keep : 64 u64      (final keep mask)
//   Trm  : 4096*64 u64 row-major; nonempty rows + row 4095 zeroed (sentinel).
// 4 dispatches (R8 skeleton — fusion refuted R7/R11/R13):
//   k_sort, k_sup (R8-exact), k_scan (MIRROR scan: scalar current-word,
//   act readlane only at word boundaries), k_out (16 blocks).
// LEDGER: R8 59.4 best. Refuted: ov-branch sup (R7/R9 +17..30), edge-walk
// (R11), 2-row sup (R12, halves wave count), last-block fusion (R13:
// cross-XCD dirty-L2 gathers +13, 1-block output +6).
// ---------------------------------------------------------------------------

__device__ __forceinline__ u64 rl64(u64 v, int l) {
    unsigned lo = __builtin_amdgcn_readlane((unsigned)v, l);
    unsigned hi = __builtin_amdgcn_readlane((unsigned)(v >> 32), l);
    return ((u64)hi << 32) | lo;
}

// K1: stable descending rank sort (R8 exact) + zero A + zero Trm row 4095.
__global__ void __launch_bounds__(256) k_sort(const float* __restrict__ res,
                                              float* __restrict__ rows,
                                              float* __restrict__ soa,
                                              u64* __restrict__ A,
                                              u64* __restrict__ Trm) {
    __shared__ float s[N_DET];
    int tid = threadIdx.x;
    if (blockIdx.x == 0) {
        if (tid < 64) A[tid] = 0ull;
        if (tid >= 64 && tid < 128)                 // sentinel row: all zeros
            Trm[(size_t)4095 * NW + (tid - 64)] = 0ull;
    }
    for (int j = tid; j < N_DET; j += 256) s[j] = res[j * 8];
    __syncthreads();
    int r = tid >> 4, c = tid & 15;
    int gi = blockIdx.x * 16 + r;
    float sc = s[gi];
    int part = 0;
    int j0 = c * 256;
    for (int j = j0; j < j0 + 256; ++j) {
        float sj = s[j];
        part += (sj > sc) || (sj == sc && j < gi);
    }
    part += __shfl_xor(part, 1, 64);
    part += __shfl_xor(part, 2, 64);
    part += __shfl_xor(part, 4, 64);
    part += __shfl_xor(part, 8, 64);
    if (c == 0) {
        int rank = part;
        float4 a = *(const float4*)(res + gi * 8);
        float4 b = *(const float4*)(res + gi * 8 + 4);
        *(float4*)(rows + rank * 8)     = a;
        *(float4*)(rows + rank * 8 + 4) = b;
        // a = (score, class, cx, cy); b = (cz, dx, dy, dz)
        float cx = a.z, cy = a.w, cz = b.x, dx = b.y, dy = b.z, dz = b.w;
        soa[0 * N_DET + rank] = cx - dx * 0.5f;
        soa[1 * N_DET + rank] = cy - dy * 0.5f;
        soa[2 * N_DET + rank] = cz - dz * 0.5f;
        soa[3 * N_DET + rank] = cx + dx * 0.5f;
        soa[4 * N_DET + rank] = cy + dy * 0.5f;
        soa[5 * N_DET + rank] = cz + dz * 0.5f;
        soa[6 * N_DET + rank] = (dx * dy) * dz;   // np.prod order ((dx*dy)*dz)
    }
}

// K2: suppression rows (R8 exact): one wave per row, upper-tri, straight-line.
__global__ void k_sup(const float* __restrict__ soa, u64* __restrict__ Trm,
                      u64* __restrict__ A) {
    int lane = threadIdx.x & 63;
    int wave = threadIdx.x >> 6;
    int i = blockIdx.x * 4 + wave;
    float ilox = soa[0*N_DET+i], iloy = soa[1*N_DET+i], iloz = soa[2*N_DET+i];
    float ihix = soa[3*N_DET+i], ihiy = soa[4*N_DET+i], ihiz = soa[5*N_DET+i];
    float ivol = soa[6*N_DET+i];
    u64 rowword = 0, rowOr = 0;
    for (int w = (i >> 6); w < NW; ++w) {
        int j = w * 64 + lane;
        float lox = soa[0*N_DET+j], loy = soa[1*N_DET+j], loz = soa[2*N_DET+j];
        float hix = soa[3*N_DET+j], hiy = soa[4*N_DET+j], hiz = soa[5*N_DET+j];
        float vol = soa[6*N_DET+j];
        float ix = fminf(ihix,hix)-fmaxf(ilox,lox); ix = fmaxf(ix,0.f);
        float iy = fminf(ihiy,hiy)-fmaxf(iloy,loy); iy = fmaxf(iy,0.f);
        float iz = fminf(ihiz,hiz)-fmaxf(iloz,loz); iz = fmaxf(iz,0.f);
        float inter = (ix * iy) * iz;             // ((x*y)*z) like np.prod
        float uni = ivol + vol - inter;           // (vol_i+vol_j)-inter
        float iou = inter / (uni + EPS);          // IEEE div
        bool sb = (iou > IOU_TR) && (j > i);
        u64 m = __ballot(sb);
        rowOr |= m;
        rowword = (lane == w) ? m : rowword;
    }
    if (rowOr) {                                  // wave-uniform branch
        Trm[(size_t)i * NW + lane] = rowword;     // coalesced 512B store
        if (lane == 0) atomicOr(&A[i >> 6], 1ull << (i & 63));
    }
}

// K3: sparse greedy scan, MIRROR version. Per row: SALU bit-test on scalar
// s_cur (dual-issues with VALU, off the VALU chain); kept rows apply their
// mask to act (vector, off-chain) and to s_cur (2 readlanes of the settled
// prefetch register). act readlane only at word boundaries (~65x). Loads
// stay in branch-free 16-row batches, 32 rows ahead (R8 pipeline).
#define FIDX(V, GB) { V = (u32)s_nlist[(GB) + (lane & 15)]; }

#define IS1(V, P, S) { u32 si_ = (u32)__builtin_amdgcn_readlane((V), (S)); \
    P##S = Trm[(size_t)si_ * NW + lane]; }

#define IS16(V, P) IS1(V,P,0) IS1(V,P,1) IS1(V,P,2) IS1(V,P,3)   \
    IS1(V,P,4) IS1(V,P,5) IS1(V,P,6) IS1(V,P,7)                  \
    IS1(V,P,8) IS1(V,P,9) IS1(V,P,10) IS1(V,P,11)                \
    IS1(V,P,12) IS1(V,P,13) IS1(V,P,14) IS1(V,P,15)

#define PR1(V, P, S) { \
    u32 si_ = (u32)__builtin_amdgcn_readlane((V), (S)); \
    u32 w_ = si_ >> 6; \
    if (w_ != s_w) {                        /* uniform, rare (~65x) */ \
        s_cur = rl64(act, (int)w_); s_w = w_; } \
    if ((s_cur >> (si_ & 63u)) & 1ull) {    /* uniform; sentinel-safe */ \
        act &= ~P##S;                       /* vector apply, off-chain */ \
        s_cur &= ~rl64(P##S, (int)w_); } }  /* scalar mirror update */

#define PR16(V, P) PR1(V,P,0) PR1(V,P,1) PR1(V,P,2) PR1(V,P,3)   \
    PR1(V,P,4) PR1(V,P,5) PR1(V,P,6) PR1(V,P,7)                  \
    PR1(V,P,8) PR1(V,P,9) PR1(V,P,10) PR1(V,P,11)                \
    PR1(V,P,12) PR1(V,P,13) PR1(V,P,14) PR1(V,P,15)

__global__ void __launch_bounds__(256, 1)
k_scan(const u64* __restrict__ Trm, const u64* __restrict__ A,
       const float* __restrict__ rows, u64* __restrict__ keep) {
    __shared__ u64 s_valid[NW];
    __shared__ u16 s_nlist[4224];
    const int tid = threadIdx.x;
    const int wv = tid >> 6;
    const int lane = tid & 63;

    for (int w = wv * 16; w < wv * 16 + 16; ++w) {
        float scw = rows[(w * 64 + lane) * 8];
        u64 m = __ballot(scw >= SCORE_TR);
        if (lane == 0) s_valid[w] = m;
    }
    __syncthreads();
    if (wv != 0) return;

    u64 act = s_valid[lane];
    u64 avA = A[lane];
    int pc = __popcll(avA);
    int inc = pc;
#pragma unroll
    for (int d = 1; d < 64; d <<= 1) {
        int t = __shfl_up(inc, d, 64);
        if (lane >= d) inc += t;
    }
    int exc = inc - pc;
    int nTotal = __shfl(inc, 63, 64);
    {   // emit this lane's nonempty-row indices (globally sorted)
        u64 m = avA; int o = exc;
        while (m) {
            int k = __builtin_ctzll(m); m &= m - 1;
            s_nlist[o++] = (u16)(lane * 64 + k);
        }
    }
    int padded = (nTotal + 63) & ~63;
    for (int t = nTotal + lane; t < padded + 128; t += 64)
        s_nlist[t] = (u16)4095;            // sentinel (Trm row 4095 zeroed)
    __threadfence_block();                 // wave-local LDS ordering

    if (padded > 0) {
        u64 pa0,pa1,pa2,pa3,pa4,pa5,pa6,pa7,
            pa8,pa9,pa10,pa11,pa12,pa13,pa14,pa15;
        u64 pb0,pb1,pb2,pb3,pb4,pb5,pb6,pb7,
            pb8,pb9,pb10,pb11,pb12,pb13,pb14,pb15;
        u32 iA0, iA1, iB0, iB1;
        u32 s_w = 0xFFFFFFFFu;             // force advance on first row
        u64 s_cur = 0ull;
        FIDX(iA0, 0)  IS16(iA0, pa)
        FIDX(iB0, 16) IS16(iB0, pb)
        int g = 0;
        while (g < padded) {
            FIDX(iA1, g + 32)
            PR16(iA0, pa)                  // rows g..g+15
            IS16(iA1, pa)                  // issue g+32
            FIDX(iB1, g + 48)
            PR16(iB0, pb)                  // rows g+16..g+31
            IS16(iB1, pb)                  // issue g+48
            g += 32;
            if (g >= padded) break;
            FIDX(iA0, g + 32)
            PR16(iA1, pa)
            IS16(iA0, pa)
            FIDX(iB0, g + 48)
            PR16(iB1, pb)
            IS16(iB0, pb)
            g += 32;
        }
    }
    keep[lane] = act;                      // final act == keep mask
}

// K4: gated output, 16 blocks x 256 threads, coalesced (R8 exact).
__global__ void k_out(const float* __restrict__ rows,
                      const u64* __restrict__ keep,
                      float* __restrict__ out) {
    int i = blockIdx.x * 256 + threadIdx.x;
    bool kp = (keep[i >> 6] >> (i & 63)) & 1ull;
    float4 a = kp ? ((const float4*)rows)[i * 2]     : make_float4(0.f, 0.f, 0.f, 0.f);
    float4 b = kp ? ((const float4*)rows)[i * 2 + 1] : make_float4(0.f, 0.f, 0.f, 0.f);
    ((float4*)out)[i * 2]     = a;
    ((float4*)out)[i * 2 + 1] = b;
}

extern "C" void kernel_launch(void* const* d_in, const int* in_sizes, int n_in,
                              void* d_out, int out_size, void* d_ws, size_t ws_size,
                              hipStream_t stream) {
    const float* res = (const float*)d_in[0];
    float* out = (float*)d_out;

    float* rows = (float*)d_ws;                       // 32768 f32
    float* soa  = rows + N_DET * 8;                   // 28672 f32
    u64* A      = (u64*)(soa + 7 * N_DET);            // 64 u64
    u64* keep   = A + NW;                             // 64 u64
    u64* Trm    = keep + NW;                          // 4096*64 u64 (row-major)

    k_sort<<<N_DET / 16, 256, 0, stream>>>(res, rows, soa, A, Trm);
    k_sup <<<N_DET / 4, 256, 0, stream>>>(soa, Trm, A);
    k_scan<<<1, 256, 0, stream>>>(Trm, A, rows, keep);
    k_out <<<16, 256, 0, stream>>>(rows, keep, out);
}

// Round 15
// 57.499 us; speedup vs baseline: 1.3134x; 1.0723x over previous
//
#include <hip/hip_runtime.h>

typedef unsigned long long u64;
typedef unsigned int u32;
typedef unsigned short u16;

#define N_DET 4096
#define NW 64               // 4096 bits = 64 u64 words
#define IOU_TR 0.3f
#define SCORE_TR 0.1f
#define EPS 1e-9f

// ---------------------------------------------------------------------------
// ws layout:
//   rows  : 4096*8 f32    (sorted detection rows)        128 KB
//   ssc   : 4096 f32      (sorted scores, compact)        16 KB
//   soaLO : 4096 float4   (lox,loy,loz,vol)               64 KB
//   soaHI : 4096 float4   (hix,hiy,hiz,0)                 64 KB
//   A     : 64 u64        (bit i = row i nonempty)
//   keep  : 64 u64
//   Trm   : 4096*64 u64   row-major; only nonempty rows written.
// 4 dispatches (R8 skeleton): k_sort, k_sup (float4-packed boxes: 2 loads
// per j instead of 7), k_scan (R8-exact chain, coalesced ssc ballots), k_out.
// LEDGER: R8 59.4 best. Refuted: ov-branch sup (R7/R9), edge-walk (R11),
// 2-row sup (R12), mirror scan (R14), last-block fusion (R7/R13).
// This round: layout-only packing — no wave-count/branch-structure changes.
// ---------------------------------------------------------------------------

__device__ __forceinline__ u64 rl64(u64 v, int l) {
    unsigned lo = __builtin_amdgcn_readlane((unsigned)v, l);
    unsigned hi = __builtin_amdgcn_readlane((unsigned)(v >> 32), l);
    return ((u64)hi << 32) | lo;
}

// K1: stable descending rank sort (R8-exact ranking) + packed outputs.
__global__ void __launch_bounds__(256) k_sort(const float* __restrict__ res,
                                              float* __restrict__ rows,
                                              float* __restrict__ ssc,
                                              float4* __restrict__ soaLO,
                                              float4* __restrict__ soaHI,
                                              u64* __restrict__ A) {
    __shared__ float s[N_DET];
    int tid = threadIdx.x;
    if (blockIdx.x == 0 && tid < 64) A[tid] = 0ull;
    for (int j = tid; j < N_DET; j += 256) s[j] = res[j * 8];
    __syncthreads();
    int r = tid >> 4, c = tid & 15;
    int gi = blockIdx.x * 16 + r;
    float sc = s[gi];
    int part = 0;
    int j0 = c * 256;
    for (int j = j0; j < j0 + 256; ++j) {
        float sj = s[j];
        part += (sj > sc) || (sj == sc && j < gi);
    }
    part += __shfl_xor(part, 1, 64);
    part += __shfl_xor(part, 2, 64);
    part += __shfl_xor(part, 4, 64);
    part += __shfl_xor(part, 8, 64);
    if (c == 0) {
        int rank = part;
        float4 a = *(const float4*)(res + gi * 8);
        float4 b = *(const float4*)(res + gi * 8 + 4);
        *(float4*)(rows + rank * 8)     = a;
        *(float4*)(rows + rank * 8 + 4) = b;
        ssc[rank] = a.x;
        // a = (score, class, cx, cy); b = (cz, dx, dy, dz)
        float cx = a.z, cy = a.w, cz = b.x, dx = b.y, dy = b.z, dz = b.w;
        soaLO[rank] = make_float4(cx - dx * 0.5f, cy - dy * 0.5f,
                                  cz - dz * 0.5f, (dx * dy) * dz); // vol in .w
        soaHI[rank] = make_float4(cx + dx * 0.5f, cy + dy * 0.5f,
                                  cz + dz * 0.5f, 0.0f);
    }
}

// K2: suppression rows (R8 structure: one wave per row, upper-tri,
// straight-line body) with float4-packed box loads (2 per j, was 7).
__global__ void k_sup(const float4* __restrict__ soaLO,
                      const float4* __restrict__ soaHI,
                      u64* __restrict__ Trm, u64* __restrict__ A) {
    int lane = threadIdx.x & 63;
    int wave = threadIdx.x >> 6;
    int i = blockIdx.x * 4 + wave;
    float4 iLO = soaLO[i];                        // (lox,loy,loz,vol)
    float4 iHI = soaHI[i];                        // (hix,hiy,hiz,-)
    u64 rowword = 0, rowOr = 0;
    for (int w = (i >> 6); w < NW; ++w) {
        int j = w * 64 + lane;
        float4 jLO = soaLO[j];
        float4 jHI = soaHI[j];
        float ix = fminf(iHI.x, jHI.x) - fmaxf(iLO.x, jLO.x); ix = fmaxf(ix, 0.f);
        float iy = fminf(iHI.y, jHI.y) - fmaxf(iLO.y, jLO.y); iy = fmaxf(iy, 0.f);
        float iz = fminf(iHI.z, jHI.z) - fmaxf(iLO.z, jLO.z); iz = fmaxf(iz, 0.f);
        float inter = (ix * iy) * iz;             // ((x*y)*z) like np.prod
        float uni = iLO.w + jLO.w - inter;        // (vol_i+vol_j)-inter
        float iou = inter / (uni + EPS);          // IEEE div
        bool sb = (iou > IOU_TR) && (j > i);
        u64 m = __ballot(sb);
        rowOr |= m;
        rowword = (lane == w) ? m : rowword;
    }
    if (rowOr) {                                  // wave-uniform branch
        Trm[(size_t)i * NW + lane] = rowword;     // coalesced 512B store
        if (lane == 0) atomicOr(&A[i >> 6], 1ull << (i & 63));
    }
}

// K3: sparse greedy scan (R8-exact chain + pipeline; ballots read compact ssc).
#define FIDX(V, GB) { V = (u32)s_nlist[(GB) + (lane & 15)]; }

#define IS1(V, P, S) { u32 si_ = (u32)__builtin_amdgcn_readlane((V), (S)); \
    P##S = Trm[(size_t)si_ * NW + lane]; }

#define IS16(V, P) IS1(V,P,0) IS1(V,P,1) IS1(V,P,2) IS1(V,P,3)   \
    IS1(V,P,4) IS1(V,P,5) IS1(V,P,6) IS1(V,P,7)                  \
    IS1(V,P,8) IS1(V,P,9) IS1(V,P,10) IS1(V,P,11)                \
    IS1(V,P,12) IS1(V,P,13) IS1(V,P,14) IS1(V,P,15)

#define PR1(V, P, S) { u32 si_ = (u32)__builtin_amdgcn_readlane((V), (S)); \
    u64 awd_ = rl64(act, (int)(si_ >> 6));                                 \
    u64 bit_ = (awd_ >> (si_ & 63u)) & 1ull;                               \
    u64 m_ = (0ull - bit_) & (0ull - (u64)(si_ != 4095u));                 \
    act &= ~(P##S & m_); }

#define PR16(V, P) PR1(V,P,0) PR1(V,P,1) PR1(V,P,2) PR1(V,P,3)   \
    PR1(V,P,4) PR1(V,P,5) PR1(V,P,6) PR1(V,P,7)                  \
    PR1(V,P,8) PR1(V,P,9) PR1(V,P,10) PR1(V,P,11)                \
    PR1(V,P,12) PR1(V,P,13) PR1(V,P,14) PR1(V,P,15)

__global__ void __launch_bounds__(256, 1)
k_scan(const u64* __restrict__ Trm, const u64* __restrict__ A,
       const float* __restrict__ ssc, u64* __restrict__ keep) {
    __shared__ u64 s_valid[NW];
    __shared__ u16 s_nlist[4224];
    const int tid = threadIdx.x;
    const int wv = tid >> 6;
    const int lane = tid & 63;

    for (int w = wv * 16; w < wv * 16 + 16; ++w) {
        float scw = ssc[w * 64 + lane];            // coalesced (was 32B stride)
        u64 m = __ballot(scw >= SCORE_TR);
        if (lane == 0) s_valid[w] = m;
    }
    __syncthreads();
    if (wv != 0) return;

    u64 act = s_valid[lane];
    u64 avA = A[lane];
    int pc = __popcll(avA);
    int inc = pc;
#pragma unroll
    for (int d = 1; d < 64; d <<= 1) {
        int t = __shfl_up(inc, d, 64);
        if (lane >= d) inc += t;
    }
    int exc = inc - pc;
    int nTotal = __shfl(inc, 63, 64);
    {   // emit this lane's nonempty-row indices (globally sorted)
        u64 m = avA; int o = exc;
        while (m) {
            int k = __builtin_ctzll(m); m &= m - 1;
            s_nlist[o++] = (u16)(lane * 64 + k);
        }
    }
    int padded = (nTotal + 63) & ~63;
    for (int t = nTotal + lane; t < padded + 128; t += 64)
        s_nlist[t] = (u16)4095;            // sentinel (masked in PR1)
    __threadfence_block();                 // wave-local LDS ordering

    if (padded > 0) {
        u64 pa0,pa1,pa2,pa3,pa4,pa5,pa6,pa7,
            pa8,pa9,pa10,pa11,pa12,pa13,pa14,pa15;
        u64 pb0,pb1,pb2,pb3,pb4,pb5,pb6,pb7,
            pb8,pb9,pb10,pb11,pb12,pb13,pb14,pb15;
        u32 iA0, iA1, iB0, iB1;
        FIDX(iA0, 0)  IS16(iA0, pa)
        FIDX(iB0, 16) IS16(iB0, pb)
        int g = 0;
        while (g < padded) {
            FIDX(iA1, g + 32)
            PR16(iA0, pa)                  // rows g..g+15
            IS16(iA1, pa)                  // issue g+32
            FIDX(iB1, g + 48)
            PR16(iB0, pb)                  // rows g+16..g+31
            IS16(iB1, pb)                  // issue g+48
            g += 32;
            if (g >= padded) break;
            FIDX(iA0, g + 32)
            PR16(iA1, pa)
            IS16(iA0, pa)
            FIDX(iB0, g + 48)
            PR16(iB1, pb)
            IS16(iB0, pb)
            g += 32;
        }
    }
    keep[lane] = act;                      // final act == keep mask
}

// K4: gated output, 16 blocks x 256 threads, coalesced (R8 exact).
__global__ void k_out(const float* __restrict__ rows,
                      const u64* __restrict__ keep,
                      float* __restrict__ out) {
    int i = blockIdx.x * 256 + threadIdx.x;
    bool kp = (keep[i >> 6] >> (i & 63)) & 1ull;
    float4 a = kp ? ((const float4*)rows)[i * 2]     : make_float4(0.f, 0.f, 0.f, 0.f);
    float4 b = kp ? ((const float4*)rows)[i * 2 + 1] : make_float4(0.f, 0.f, 0.f, 0.f);
    ((float4*)out)[i * 2]     = a;
    ((float4*)out)[i * 2 + 1] = b;
}

extern "C" void kernel_launch(void* const* d_in, const int* in_sizes, int n_in,
                              void* d_out, int out_size, void* d_ws, size_t ws_size,
                              hipStream_t stream) {
    const float* res = (const float*)d_in[0];
    float* out = (float*)d_out;

    float*  rows  = (float*)d_ws;                     // 32768 f32
    float*  ssc   = rows + N_DET * 8;                 // 4096 f32
    float4* soaLO = (float4*)(ssc + N_DET);           // 4096 float4
    float4* soaHI = soaLO + N_DET;                    // 4096 float4
    u64*    A     = (u64*)(soaHI + N_DET);            // 64 u64
    u64*    keep  = A + NW;                           // 64 u64
    u64*    Trm   = keep + NW;                        // 4096*64 u64

    k_sort<<<N_DET / 16, 256, 0, stream>>>(res, rows, ssc, soaLO, soaHI, A);
    k_sup <<<N_DET / 4, 256, 0, stream>>>(soaLO, soaHI, Trm, A);
    k_scan<<<1, 256, 0, stream>>>(Trm, A, ssc, keep);
    k_out <<<16, 256, 0, stream>>>(rows, keep, out);
}